// Round 1
// baseline (410.651 us; speedup 1.0000x reference)
//
#include <hip/hip_runtime.h>

// MX fp8-e4m3 fake quantization, block = 32 contiguous fp32 elements.
//
// Mapping: 1 thread = 1 float4 (4 elems) -> 1 MX block = 8 consecutive lanes.
// Per-block amax reduced with 3 shfl_xor ops within 8-lane groups (no LDS).
//
// All exponent math is done on the fp32 bit pattern (floor(log2(x)) ==
// unbiased exponent for normals; subnormal/zero clamped to -126, which is
// equivalent after the downstream max/clip). Every scale is an exact power
// of two, so the only rounding op is rintf (round-half-even, == jnp.round).

__global__ __launch_bounds__(256) void mx_fp8_qdq_kernel(
    const float4* __restrict__ in, float4* __restrict__ out, int n4) {
  int i = blockIdx.x * blockDim.x + threadIdx.x;
  if (i >= n4) return;

  float4 v = in[i];

  // ---- per-block amax (32 elems = 8 lanes x float4) ----
  float a = fmaxf(fmaxf(fabsf(v.x), fabsf(v.y)), fmaxf(fabsf(v.z), fabsf(v.w)));
  a = fmaxf(a, __shfl_xor(a, 1, 8));
  a = fmaxf(a, __shfl_xor(a, 2, 8));
  a = fmaxf(a, __shfl_xor(a, 4, 8));

  // shared_exp = clip(floor(log2(amax or tiny)) - 8, -127, 127)
  int eb = (int)((__float_as_uint(a) >> 23) & 0xFF);
  if (eb < 1) eb = 1;              // amax zero/subnormal -> exponent -126
  int s = eb - 127 - 8;            // floor(log2(amax)) - EMAX
  if (s < -127) s = -127;          // upper clip unreachable (eb<=254 -> s<=119)

  // inv_scale = 2^-s ; -s in [-119,127] -> always a normal fp32
  const float inv_scale = __uint_as_float((unsigned)(127 - s) << 23);

  // ---- element-wise e4m3 quantize of xs = x * 2^-s ----
  // |xs| < 512 always, so priv_exp pe in [-6, 8].
  #define QDQ1(x)                                                              \
    ({                                                                         \
      float xs_ = (x) * inv_scale;                                             \
      int pe_ = (int)((__float_as_uint(xs_) >> 23) & 0xFF);                    \
      pe_ = (pe_ < 1 ? 1 : pe_) - 127;                                         \
      if (pe_ < -6) pe_ = -6;                                                  \
      /* 2^(3-pe): biased exp in [121,136] -> normal */                        \
      float ips_ = __uint_as_float((unsigned)(130 - pe_) << 23);               \
      float r_ = rintf(xs_ * ips_);         /* round-half-even mantissa */     \
      float ps_ = __uint_as_float((unsigned)(124 + pe_) << 23); /* 2^(pe-3) */ \
      float q_ = r_ * ps_;                  /* exact: small int * pow2 */      \
      q_ = fminf(fmaxf(q_, -448.0f), 448.0f);                                  \
      ldexpf(q_, s);                        /* q * 2^s, v_ldexp_f32 */         \
    })

  float4 o;
  o.x = QDQ1(v.x);
  o.y = QDQ1(v.y);
  o.z = QDQ1(v.z);
  o.w = QDQ1(v.w);
  #undef QDQ1

  out[i] = o;
}

extern "C" void kernel_launch(void* const* d_in, const int* in_sizes, int n_in,
                              void* d_out, int out_size, void* d_ws, size_t ws_size,
                              hipStream_t stream) {
  const float4* in = (const float4*)d_in[0];
  float4* out = (float4*)d_out;
  int n4 = in_sizes[0] / 4;  // 8192*8192/4 = 16777216, divisible by 256
  int block = 256;
  int grid = (n4 + block - 1) / block;
  mx_fp8_qdq_kernel<<<grid, block, 0, stream>>>(in, out, n4);
}